// Round 6
// baseline (557.093 us; speedup 1.0000x reference)
//
#include <hip/hip_runtime.h>

#define LN2 0.6931471805599453f

constexpr int T = 512, N = 32, C = 4000, S = 64;
constexpr int TN  = T * N;
constexpr int LPW = S + 1;        // 65: [blank, label_0..label_63] probs per (n,t)
constexpr int SLAB_T = 32;        // timesteps per published slab
constexpr int NSLAB  = T / SLAB_T;        // 16
constexpr int RPS    = SLAB_T * N;        // rows per slab = 1024
constexpr int NCONS_BLK = 8;
constexpr int NPROD_BLK = 248;
constexpr int NBLK  = NCONS_BLK + NPROD_BLK;  // 256 blocks (<= 1/CU)
constexpr int NPW   = NPROD_BLK * 4;          // 992 producer waves
constexpr int CT    = 16;                     // consumer reg-chunk (2 per slab)

// ---------------- DPP helpers ------------------------------------------------
__device__ __forceinline__ float dpp_shr1_zero(float x) {
    int r = __builtin_amdgcn_update_dpp(0, __float_as_int(x),
                                        0x138 /*wave_shr:1*/, 0xf, 0xf, false);
    return __int_as_float(r);
}
template <int CTRL>
__device__ __forceinline__ float dpp_max_step(float x) {
    int t = __builtin_amdgcn_update_dpp(__float_as_int(x), __float_as_int(x),
                                        CTRL, 0xf, 0xf, false);
    return fmaxf(x, __int_as_float(t));
}
__device__ __forceinline__ float wave_max_bcast(float x) {
    x = dpp_max_step<0xB1>(x);    // xor 1
    x = dpp_max_step<0x4E>(x);    // xor 2
    x = dpp_max_step<0x141>(x);   // xor 4
    x = dpp_max_step<0x140>(x);   // xor 8
    x = dpp_max_step<0x142>(x);   // row_bcast15
    x = dpp_max_step<0x143>(x);   // row_bcast31 -> lane 63 has wave max
    return __int_as_float(__builtin_amdgcn_readlane(__float_as_int(x), 63));
}
// rescale alphas to a 2^100 anchor; v_ldexp_f32 is exact & safe for any k.
__device__ __forceinline__ void renorm(float& a0, float& a1, float& aX, int& SH) {
    float g = wave_max_bcast(fmaxf(a0, fmaxf(a1, aX)));
    unsigned bits = __float_as_uint(g);
    int e = (bits == 0u) ? 100 : (int)(bits >> 23) - 127;   // zero -> k=0
    int k = 100 - e;
    a0 = ldexpf(a0, k); a1 = ldexpf(a1, k); aX = ldexpf(aX, k);
    SH += k;
}

// ---------------- producer: one (t,n) row -> 65 softmax probs ----------------
__device__ __forceinline__ void produce_row(
    const float* __restrict__ x, const int* __restrict__ labels,
    float* __restrict__ pp, int r, int lane)
{
    const float*  rp  = x + (size_t)r * C;
    const float4* rp4 = reinterpret_cast<const float4*>(rp);
    float m = -INFINITY, s = 0.f;
    #pragma unroll
    for (int k = 0; k < 15; ++k) {                 // 960 of 1000 float4s
        float4 v = rp4[lane + 64 * k];
        float mv = fmaxf(fmaxf(v.x, v.y), fmaxf(v.z, v.w));
        float s4 = __expf(v.x - mv) + __expf(v.y - mv) +
                   __expf(v.z - mv) + __expf(v.w - mv);
        float nm = fmaxf(m, mv);
        s = s * __expf(m - nm) + s4 * __expf(mv - nm);
        m = nm;
    }
    if (lane < 40) {                               // tail 40 float4s
        float4 v = rp4[960 + lane];
        float mv = fmaxf(fmaxf(v.x, v.y), fmaxf(v.z, v.w));
        float s4 = __expf(v.x - mv) + __expf(v.y - mv) +
                   __expf(v.z - mv) + __expf(v.w - mv);
        float nm = fmaxf(m, mv);
        s = s * __expf(m - nm) + s4 * __expf(mv - nm);
        m = nm;
    }
    for (int off = 32; off; off >>= 1) {
        float om = __shfl_xor(m, off), os = __shfl_xor(s, off);
        float nm = fmaxf(m, om);
        s = s * __expf(m - nm) + os * __expf(om - nm);
        m = nm;
    }
    float logZ = m + __logf(s);
    int t = r >> 5, n = r & 31;                    // r = t*N + n, N=32
    int c = labels[n * S + lane];
    float* outp = pp + ((size_t)n * T + t) * LPW;
    outp[1 + lane] = __expf(rp[c] - logZ);
    if (lane == 0) outp[0] = __expf(rp[0] - logZ);
}

#define LOADC(CB, CL, cc) do {                                             \
    const float* cp_ = bp + (size_t)(cc) * (CT * LPW);                     \
    _Pragma("unroll")                                                      \
    for (int d_ = 0; d_ < CT; ++d_) {                                      \
        CB[d_] = cp_[d_ * LPW];                                            \
        CL[d_] = cp_[d_ * LPW + 1 + lane];                                 \
    } } while (0)

#define COMPC(CB, CL, cc) do {                                             \
    int tb_ = (cc) * CT;                                                   \
    _Pragma("unroll")                                                      \
    for (int d_ = 0; d_ < CT; ++d_) {                                      \
        int t_ = tb_ + d_;                                                 \
        bool act_ = (unsigned)(t_ - 1) < (unsigned)(Tin - 1);              \
        float cb_ = CB[d_], cl_ = CL[d_];                                  \
        float p1_ = dpp_shr1_zero(a1);          /* alpha[2i-1] */          \
        float na0_ = (a0 + p1_) * cb_;          /* blank pos 2i */         \
        float ts_  = a0 + a1 + (skip_ok ? p1_ : 0.f);                      \
        float na1_ = ts_ * cl_;                 /* label pos 2i+1 */       \
        float naX_ = (aX + a1) * cb_;           /* pos 128 (lane 63) */    \
        a0 = act_ ? na0_ : a0;                                             \
        a1 = act_ ? na1_ : a1;                                             \
        aX = act_ ? naX_ : aX;                                             \
        if ((d_ & 3) == 3) renorm(a0, a1, aX, SH);                         \
    } } while (0)

// ---------------- fused kernel ----------------------------------------------
// blocks 0..7: consumers (alpha recursion, 1 wave per n, spin on slab counters)
// blocks 8..255: producers (softmax rows in time-slab order, release-publish)
// Deadlock-free: producers never wait; consumers wait only on producers.
__global__ __launch_bounds__(256) void k_ctc_fused(
    const float* __restrict__ x, const int* __restrict__ labels,
    const int* __restrict__ input_len, const int* __restrict__ label_len,
    float* __restrict__ pp, int* __restrict__ cnt,
    float* __restrict__ loss, float* __restrict__ out)
{
    int bid = blockIdx.x, tid = threadIdx.x;
    int wv = tid >> 6, lane = tid & 63;

    if (bid >= NCONS_BLK) {
        // ---------------- producer ----------------
        int pw = (bid - NCONS_BLK) * 4 + wv;       // 0..991
        for (int s = 0; s < NSLAB; ++s) {
            produce_row(x, labels, pp, s * RPS + pw, lane);
            if (lane == 0)
                __hip_atomic_fetch_add(&cnt[s], 1, __ATOMIC_RELEASE,
                                       __HIP_MEMORY_SCOPE_AGENT);
            int j = pw - s * 32;                   // rotating 2nd-row duty
            if (0 <= j && j < RPS - NPW) {         // 32 extra rows per slab
                produce_row(x, labels, pp, s * RPS + NPW + j, lane);
                if (lane == 0)
                    __hip_atomic_fetch_add(&cnt[s], 1, __ATOMIC_RELEASE,
                                           __HIP_MEMORY_SCOPE_AGENT);
            }
        }
        return;
    }

    // ---------------- consumer: alpha recursion for batch n ----------------
    int n = bid * 4 + wv;
    const float* bp = pp + (size_t)n * T * LPW;
    int Tin = input_len[n], Sl = label_len[n];

    int li   = labels[n * S + lane];
    int lim1 = lane ? labels[n * S + lane - 1] : -1;
    bool skip_ok = (lane > 0) && (li != 0) && (li != lim1);

    float a0 = 0.f, a1 = 0.f, aX = 0.f;
    int   SH = 0;
    float cbA[CT], clA[CT], cbB[CT], clB[CT];

    for (int s = 0; s < NSLAB; ++s) {
        // wait for slab s (rows counted per wave; target = RPS)
        while (__hip_atomic_load(&cnt[s], __ATOMIC_ACQUIRE,
                                 __HIP_MEMORY_SCOPE_AGENT) < RPS / 64 * 64 + (RPS & 63) /* = RPS */)
            __builtin_amdgcn_s_sleep(2);
        LOADC(cbA, clA, 2 * s);
        LOADC(cbB, clB, 2 * s + 1);
        if (s == 0) {                              // t=0 init from slab 0
            a0 = (lane == 0) ? cbA[0] : 0.f;       // bp[0]
            a1 = (lane == 0 && Sl > 0) ? clA[0] : 0.f;  // bp[1] (lane 0)
        }
        COMPC(cbA, clA, 2 * s);
        COMPC(cbB, clB, 2 * s + 1);
    }

    float a_last = (Sl >= S) ? __shfl(aX, 63) : __shfl(a0, Sl);
    float a_prev_raw = __shfl(a1, (Sl > 0) ? (Sl - 1) : 0);
    float a_prev = (Sl > 0) ? a_prev_raw : 0.f;
    if (lane == 0) {
        float sum  = a_last + a_prev;
        float ll2  = log2f(sum) - (float)SH;       // log2 P
        float l    = -ll2 * LN2;
        if (!(l < 5e29f)) l = 0.f;                 // zero_infinity (+NaN)
        loss[n] = l;
        __hip_atomic_fetch_add(&cnt[NSLAB], 1, __ATOMIC_RELEASE,
                               __HIP_MEMORY_SCOPE_AGENT);
    }

    // consumer wave n==0 folds the final N-way sum (replaces k_reduce)
    if (n == 0) {
        while (__hip_atomic_load(&cnt[NSLAB], __ATOMIC_ACQUIRE,
                                 __HIP_MEMORY_SCOPE_AGENT) < N)
            __builtin_amdgcn_s_sleep(2);
        float v = (lane < N) ? loss[lane] : 0.f;
        for (int off = 32; off; off >>= 1) v += __shfl_xor(v, off);
        if (lane == 0) out[0] = v;
    }
}

extern "C" void kernel_launch(void* const* d_in, const int* in_sizes, int n_in,
                              void* d_out, int out_size, void* d_ws, size_t ws_size,
                              hipStream_t stream) {
    const float* x       = (const float*)d_in[0];
    const int*   labels  = (const int*)d_in[1];
    const int*   in_len  = (const int*)d_in[2];
    const int*   lab_len = (const int*)d_in[3];
    float* out  = (float*)d_out;
    float* pp   = (float*)d_ws;                          // TN*65 floats
    float* loss = pp + (size_t)TN * LPW;                 // N floats
    int*   cnt  = (int*)(loss + N);                      // NSLAB+1 ints

    hipMemsetAsync(cnt, 0, (NSLAB + 1) * sizeof(int), stream);
    k_ctc_fused<<<NBLK, 256, 0, stream>>>(x, labels, in_len, lab_len,
                                          pp, cnt, loss, out);
}

// Round 7
// 95.714 us; speedup vs baseline: 5.8204x; 5.8204x over previous
//
#include <hip/hip_runtime.h>

#define LN2 0.6931471805599453f

constexpr int T = 512, N = 32, C = 4000, S = 64;
constexpr int TN   = T * N;
constexpr int ROWF = 68;          // padded row stride in floats (272B, 16B-aligned)
constexpr int CT   = 16;          // timesteps per LDS chunk
constexpr int NC   = T / CT;      // 32 chunks

// ---------------- Kernel 1: softmax probabilities at the 65 needed classes ---
// One wave per (t,n) row; streaming logsumexp over C=4000; writes PROBABILITIES
// to padded transposed layout pp[n][t][ROWF] ([0]=blank, [1+s]=label s).
__global__ __launch_bounds__(256) void k_softmax_probs(
    const float* __restrict__ x, const int* __restrict__ labels,
    float* __restrict__ pp)
{
    int row  = blockIdx.x * 4 + (threadIdx.x >> 6);   // row = t*N + n
    int lane = threadIdx.x & 63;
    const float*  rp  = x + (size_t)row * C;
    const float4* rp4 = reinterpret_cast<const float4*>(rp);

    float m = -INFINITY, s = 0.f;
    #pragma unroll
    for (int k = 0; k < 15; ++k) {                 // 960 of 1000 float4s
        float4 v = rp4[lane + 64 * k];
        float mv = fmaxf(fmaxf(v.x, v.y), fmaxf(v.z, v.w));
        float s4 = __expf(v.x - mv) + __expf(v.y - mv) +
                   __expf(v.z - mv) + __expf(v.w - mv);
        float nm = fmaxf(m, mv);
        s = s * __expf(m - nm) + s4 * __expf(mv - nm);
        m = nm;
    }
    if (lane < 40) {                               // tail 40 float4s
        float4 v = rp4[960 + lane];
        float mv = fmaxf(fmaxf(v.x, v.y), fmaxf(v.z, v.w));
        float s4 = __expf(v.x - mv) + __expf(v.y - mv) +
                   __expf(v.z - mv) + __expf(v.w - mv);
        float nm = fmaxf(m, mv);
        s = s * __expf(m - nm) + s4 * __expf(mv - nm);
        m = nm;
    }
    for (int off = 32; off; off >>= 1) {
        float om = __shfl_xor(m, off), os = __shfl_xor(s, off);
        float nm = fmaxf(m, om);
        s = s * __expf(m - nm) + os * __expf(om - nm);
        m = nm;
    }
    float logZ = m + __logf(s);

    int t = row >> 5, n = row & 31;                // r = t*N + n, N = 32
    int c = labels[n * S + lane];
    float* outp = pp + ((size_t)n * T + t) * ROWF;
    outp[1 + lane] = __expf(rp[c] - logZ);
    if (lane == 0) outp[0] = __expf(rp[0] - logZ);
}

// ---------------- DPP helpers ------------------------------------------------
__device__ __forceinline__ float dpp_shr1_zero(float x) {
    int r = __builtin_amdgcn_update_dpp(0, __float_as_int(x),
                                        0x138 /*wave_shr:1*/, 0xf, 0xf, false);
    return __int_as_float(r);
}
template <int CTRL>
__device__ __forceinline__ float dpp_max_step(float x) {
    int t = __builtin_amdgcn_update_dpp(__float_as_int(x), __float_as_int(x),
                                        CTRL, 0xf, 0xf, false);
    return fmaxf(x, __int_as_float(t));
}
__device__ __forceinline__ float wave_max_bcast(float x) {
    x = dpp_max_step<0xB1>(x);    // xor 1
    x = dpp_max_step<0x4E>(x);    // xor 2
    x = dpp_max_step<0x141>(x);   // xor 4
    x = dpp_max_step<0x140>(x);   // xor 8
    x = dpp_max_step<0x142>(x);   // row_bcast15
    x = dpp_max_step<0x143>(x);   // row_bcast31 -> lane 63 has wave max
    return __int_as_float(__builtin_amdgcn_readlane(__float_as_int(x), 63));
}
// rescale alphas to a 2^100 anchor; v_ldexp_f32 is exact & safe for any k.
__device__ __forceinline__ void renorm(float& a0, float& a1, float& aX, int& SH) {
    float g = wave_max_bcast(fmaxf(a0, fmaxf(a1, aX)));
    unsigned bits = __float_as_uint(g);
    int e = (bits == 0u) ? 100 : (int)(bits >> 23) - 127;   // zero -> k=0
    int k = 100 - e;
    a0 = ldexpf(a0, k); a1 = ldexpf(a1, k); aX = ldexpf(aX, k);
    SH += k;
}

// ---------------- Kernel 2: alpha recursion, linear domain ------------------
// ONE wave per batch element. LDS double-buffered 16-step chunks staged via
// global_load_lds DMA (unsinkable by the compiler) + hand-counted vmcnt.
// Lane i owns lattice positions 2i, 2i+1; lane 63 also owns 128.
__global__ __launch_bounds__(64) void k_ctc_alpha(
    const float* __restrict__ pp, const int* __restrict__ labels,
    const int* __restrict__ input_len, const int* __restrict__ label_len,
    float* __restrict__ loss_out)
{
    __shared__ float lds[2][CT][256];   // 32 KB: 2 chunks x 16 t x 1024B DMA row
    const int n = blockIdx.x, lane = threadIdx.x;
    const float* bp = pp + (size_t)n * T * ROWF;
    const int Tin = input_len[n], Sl = label_len[n];

    const int li   = labels[n * S + lane];
    const int lim1 = lane ? labels[n * S + lane - 1] : -1;
    const bool skip_ok = (lane > 0) && (li != 0) && (li != lim1);

    // drain label/length loads so DMA vmcnt arithmetic below is exact
    asm volatile("s_waitcnt vmcnt(0)" ::: "memory");
    __builtin_amdgcn_sched_barrier(0);

    float a0 = 0.f, a1 = 0.f, aX = 0.f;
    int SH = 0;

    // 16 dwordx4 DMA loads per chunk: lane covers bytes [lane*16, lane*16+16)
    // of each padded row (row floats 0..64 live in lanes 0..16's slots).
#define ISSUE(cc) do {                                                        \
    const float* cp_ = bp + (size_t)(cc) * CT * ROWF;                         \
    _Pragma("unroll")                                                         \
    for (int d_ = 0; d_ < CT; ++d_)                                           \
        __builtin_amdgcn_global_load_lds(cp_ + (size_t)d_ * ROWF + lane * 4,  \
                                         &lds[(cc) & 1][d_][0], 16, 0, 0);    \
    } while (0)

#define STEP(cc, dd) do {                                                     \
    float cb_ = lds[(cc) & 1][dd][0];            /* blank p (broadcast) */    \
    float cl_ = lds[(cc) & 1][dd][1 + lane];     /* label p */                \
    float p1_ = dpp_shr1_zero(a1);               /* alpha[2i-1] */            \
    float na0_ = (a0 + p1_) * cb_;               /* blank pos 2i */           \
    float ts_  = a0 + a1 + (skip_ok ? p1_ : 0.f);                             \
    float na1_ = ts_ * cl_;                      /* label pos 2i+1 */         \
    float naX_ = (aX + a1) * cb_;                /* pos 128 (lane 63) */      \
    int t_ = (cc) * CT + (dd);                                                \
    bool act_ = (unsigned)(t_ - 1) < (unsigned)(Tin - 1);                     \
    a0 = act_ ? na0_ : a0;                                                    \
    a1 = act_ ? na1_ : a1;                                                    \
    aX = act_ ? naX_ : aX;                                                    \
    if (((dd) & 3) == 3) renorm(a0, a1, aX, SH);                              \
} while (0)

    ISSUE(0);
    ISSUE(1);

    // ---- chunk 0: t=0 init + steps t=1..15
    asm volatile("s_waitcnt vmcnt(16)" ::: "memory");   // chunk 0 landed
    __builtin_amdgcn_sched_barrier(0);
    a0 = (lane == 0) ? lds[0][0][0] : 0.f;
    a1 = (lane == 0 && Sl > 0) ? lds[0][0][1] : 0.f;
    #pragma unroll
    for (int d = 1; d < CT; ++d) STEP(0, d);
    __builtin_amdgcn_sched_barrier(0);                  // keep ds_reads above
    ISSUE(2);

    for (int c = 1; c < NC; ++c) {
        if (c < NC - 1) asm volatile("s_waitcnt vmcnt(16)" ::: "memory");
        else            asm volatile("s_waitcnt vmcnt(0)"  ::: "memory");
        __builtin_amdgcn_sched_barrier(0);
        #pragma unroll
        for (int d = 0; d < CT; ++d) STEP(c, d);
        if (c + 2 < NC) {
            __builtin_amdgcn_sched_barrier(0);          // ds_reads done first
            ISSUE(c + 2);
        }
    }
#undef ISSUE
#undef STEP

    // loss_n = -log(alpha[2*Sl] + alpha[2*Sl-1]) with accumulated 2^SH scale
    float a_last = (Sl >= S) ? __shfl(aX, 63) : __shfl(a0, Sl);
    float a_prev_raw = __shfl(a1, (Sl > 0) ? (Sl - 1) : 0);
    float a_prev = (Sl > 0) ? a_prev_raw : 0.f;
    if (lane == 0) {
        float sum  = a_last + a_prev;
        float ll2  = log2f(sum) - (float)SH;           // log2 P
        float loss = -ll2 * LN2;
        if (!(loss < 5e29f)) loss = 0.f;               // zero_infinity (+NaN)
        loss_out[n] = loss;
    }
}

// ---------------- Kernel 3: final sum ---------------------------------------
__global__ __launch_bounds__(64) void k_reduce(
    const float* __restrict__ loss, float* __restrict__ out)
{
    int lane = threadIdx.x;
    float v = (lane < N) ? loss[lane] : 0.f;
    for (int off = 32; off; off >>= 1) v += __shfl_xor(v, off);
    if (lane == 0) out[0] = v;
}

extern "C" void kernel_launch(void* const* d_in, const int* in_sizes, int n_in,
                              void* d_out, int out_size, void* d_ws, size_t ws_size,
                              hipStream_t stream) {
    const float* x       = (const float*)d_in[0];
    const int*   labels  = (const int*)d_in[1];
    const int*   in_len  = (const int*)d_in[2];
    const int*   lab_len = (const int*)d_in[3];
    float* out  = (float*)d_out;
    float* pp   = (float*)d_ws;                          // TN*ROWF floats
    float* loss = pp + (size_t)TN * ROWF + 256;          // +1KB pad (DMA over-read)

    k_softmax_probs<<<TN / 4, 256, 0, stream>>>(x, labels, pp);
    k_ctc_alpha<<<N, 64, 0, stream>>>(pp, labels, in_len, lab_len, loss);
    k_reduce<<<1, 64, 0, stream>>>(loss, out);
}

// Round 8
// 90.392 us; speedup vs baseline: 6.1631x; 1.0589x over previous
//
#include <hip/hip_runtime.h>

#define LN2 0.6931471805599453f

constexpr int T = 512, N = 32, C = 4000, S = 64;
constexpr int TN   = T * N;
constexpr int ROWF = 68;          // padded row stride in floats (272B, 16B-aligned)
constexpr int CT   = 16;          // timesteps per LDS chunk
constexpr int NC   = T / CT;      // 32 chunks

// ---------------- Kernel 1: softmax probabilities at the 65 needed classes ---
__global__ __launch_bounds__(256) void k_softmax_probs(
    const float* __restrict__ x, const int* __restrict__ labels,
    float* __restrict__ pp)
{
    int row  = blockIdx.x * 4 + (threadIdx.x >> 6);   // row = t*N + n
    int lane = threadIdx.x & 63;
    const float*  rp  = x + (size_t)row * C;
    const float4* rp4 = reinterpret_cast<const float4*>(rp);

    float m = -INFINITY, s = 0.f;
    #pragma unroll
    for (int k = 0; k < 15; ++k) {                 // 960 of 1000 float4s
        float4 v = rp4[lane + 64 * k];
        float mv = fmaxf(fmaxf(v.x, v.y), fmaxf(v.z, v.w));
        float s4 = __expf(v.x - mv) + __expf(v.y - mv) +
                   __expf(v.z - mv) + __expf(v.w - mv);
        float nm = fmaxf(m, mv);
        s = s * __expf(m - nm) + s4 * __expf(mv - nm);
        m = nm;
    }
    if (lane < 40) {                               // tail 40 float4s
        float4 v = rp4[960 + lane];
        float mv = fmaxf(fmaxf(v.x, v.y), fmaxf(v.z, v.w));
        float s4 = __expf(v.x - mv) + __expf(v.y - mv) +
                   __expf(v.z - mv) + __expf(v.w - mv);
        float nm = fmaxf(m, mv);
        s = s * __expf(m - nm) + s4 * __expf(mv - nm);
        m = nm;
    }
    for (int off = 32; off; off >>= 1) {
        float om = __shfl_xor(m, off), os = __shfl_xor(s, off);
        float nm = fmaxf(m, om);
        s = s * __expf(m - nm) + os * __expf(om - nm);
        m = nm;
    }
    float logZ = m + __logf(s);

    int t = row >> 5, n = row & 31;                // row = t*N + n, N = 32
    int c = labels[n * S + lane];
    float* outp = pp + ((size_t)n * T + t) * ROWF;
    outp[1 + lane] = __expf(rp[c] - logZ);
    if (lane == 0) outp[0] = __expf(rp[0] - logZ);
}

// ---------------- DPP helpers ------------------------------------------------
__device__ __forceinline__ float dpp_shr1_zero(float x) {
    int r = __builtin_amdgcn_update_dpp(0, __float_as_int(x),
                                        0x138 /*wave_shr:1*/, 0xf, 0xf, false);
    return __int_as_float(r);
}
template <int CTRL>
__device__ __forceinline__ float dpp_max_step(float x) {
    int t = __builtin_amdgcn_update_dpp(__float_as_int(x), __float_as_int(x),
                                        CTRL, 0xf, 0xf, false);
    return fmaxf(x, __int_as_float(t));
}
__device__ __forceinline__ float wave_max_bcast(float x) {
    x = dpp_max_step<0xB1>(x);    // xor 1
    x = dpp_max_step<0x4E>(x);    // xor 2
    x = dpp_max_step<0x141>(x);   // xor 4
    x = dpp_max_step<0x140>(x);   // xor 8
    x = dpp_max_step<0x142>(x);   // row_bcast15
    x = dpp_max_step<0x143>(x);   // row_bcast31 -> lane 63 has wave max
    return __int_as_float(__builtin_amdgcn_readlane(__float_as_int(x), 63));
}
// apply a power-of-2 rescale putting max(g) near 2^target (exact, any k safe)
__device__ __forceinline__ void renorm_apply(float g, float& a0, float& a1,
                                             float& aX, int& SH, int target) {
    unsigned bits = __float_as_uint(g);
    int k = (bits == 0u) ? 0 : (target - ((int)(bits >> 23) - 127));
    a0 = ldexpf(a0, k); a1 = ldexpf(a1, k); aX = ldexpf(aX, k);
    SH += k;
}

// ---------------- alpha recursion steps (linear probability domain) ----------
// Lane i owns lattice positions 2i (blank), 2i+1 (label i); lane 63 also 128.
__device__ __forceinline__ void single_step(const float* R, int lane, float skf,
                                            float& a0, float& a1, float& aX) {
    float cb = R[0], cl = R[1 + lane];
    float p1 = dpp_shr1_zero(a1);
    float n0 = (a0 + p1) * cb;
    float n1 = fmaf(skf, p1, a0 + a1) * cl;
    float nX = (aX + a1) * cb;
    a0 = n0; a1 = n1; aX = nX;
}

// Two composed timesteps: alpha(t+2) = M_{t+1} M_t alpha(t), bandwidth 5.
// Coefficients (A..Y2) are independent of alpha -> fill issue-stall slots;
// the alpha-dependent chain is 3 DPPs + a depth-3 fma tree per TWO steps.
__device__ __forceinline__ void pair_step(const float* R0, const float* R1,
    int lane, float skf, float skUf, float skk,
    float& a0, float& a1, float& aX)
{
    float cb1 = R0[0], cl1 = R0[1 + lane];
    float cb2 = R1[0], cl2 = R1[1 + lane];
    float clU = dpp_shr1_zero(cl1);        // cl_t of previous lane
    float W   = clU * cl2;
    float A   = cb1 * cb2;
    float B   = clU * cb2;
    float Cc  = A + B;
    float D   = skUf * B;
    float s1  = cb1 + cl1;
    float E   = s1 * cl2;
    float F   = cl1 * cl2;
    float G   = skf * W;
    float H   = fmaf(skf, F + W, cb1 * cl2);
    float I   = skk * W;
    float Y0  = cl1 * cb2;
    float Y1  = s1 * cb2;
    float Y2  = skf * Y0;
    float p1  = dpp_shr1_zero(a1);         // alpha[2i-1]
    float p0  = dpp_shr1_zero(a0);         // alpha[2i-2]
    float p2  = dpp_shr1_zero(p1);         // alpha[2i-3]
    float n0  = fmaf(p0, B, a0 * A) + fmaf(p2, D, p1 * Cc);
    float n1  = fmaf(a1, F, a0 * E) + fmaf(p2, I, fmaf(p1, H, p0 * G));
    float nX  = fmaf(a1, Y1, aX * A) + fmaf(p1, Y2, a0 * Y0);
    a0 = n0; a1 = n1; aX = nX;
}

// ---------------- Kernel 2: one wave per batch element ----------------------
__global__ __launch_bounds__(64) void k_ctc_alpha(
    const float* __restrict__ pp, const int* __restrict__ labels,
    const int* __restrict__ input_len, const int* __restrict__ label_len,
    float* __restrict__ loss_out)
{
    __shared__ float lds[2][CT][256];   // 32 KB: 2 chunks x 16 t x 1024B DMA row
    const int n = blockIdx.x, lane = threadIdx.x;
    const float* bp = pp + (size_t)n * T * ROWF;
    const int Tin = input_len[n], Sl = label_len[n];

    const int li   = labels[n * S + lane];
    const int lim1 = lane ? labels[n * S + lane - 1] : -1;
    const bool skip_ok = (lane > 0) && (li != 0) && (li != lim1);
    const float skf  = skip_ok ? 1.f : 0.f;
    const float skUf = dpp_shr1_zero(skf);
    const float skk  = skf * skUf;

    // drain label/length loads so DMA vmcnt arithmetic below is exact
    asm volatile("s_waitcnt vmcnt(0)" ::: "memory");
    __builtin_amdgcn_sched_barrier(0);

    float a0 = 0.f, a1 = 0.f, aX = 0.f;
    int SH = 0;

#define ISSUE(cc) do {                                                        \
    const float* cp_ = bp + (size_t)(cc) * CT * ROWF;                         \
    _Pragma("unroll")                                                         \
    for (int d_ = 0; d_ < CT; ++d_)                                           \
        __builtin_amdgcn_global_load_lds(cp_ + (size_t)d_ * ROWF + lane * 4,  \
                                         &lds[(cc) & 1][d_][0], 16, 0, 0);    \
    } while (0)

// 4 composed steps (8 timesteps) + overlapped renorm (snapshot max before,
// DPP tree scheduled into the pairs' stall slots, pow2 apply after).
#define WIN4(BUF, D0) do {                                                    \
    float gs_ = fmaxf(fmaxf(a0, a1), aX);                                     \
    pair_step(&lds[BUF][D0    ][0], &lds[BUF][D0 + 1][0], lane, skf, skUf, skk, a0, a1, aX); \
    pair_step(&lds[BUF][D0 + 2][0], &lds[BUF][D0 + 3][0], lane, skf, skUf, skk, a0, a1, aX); \
    pair_step(&lds[BUF][D0 + 4][0], &lds[BUF][D0 + 5][0], lane, skf, skUf, skk, a0, a1, aX); \
    pair_step(&lds[BUF][D0 + 6][0], &lds[BUF][D0 + 7][0], lane, skf, skUf, skk, a0, a1, aX); \
    renorm_apply(wave_max_bcast(gs_), a0, a1, aX, SH, 90);                    \
} while (0)

    ISSUE(0);
    ISSUE(1);

    if (Tin == T) {
        // ---------------- hot path: no per-step freeze masking ----------------
        asm volatile("s_waitcnt vmcnt(16)" ::: "memory");   // chunk 0 landed
        __builtin_amdgcn_sched_barrier(0);
        a0 = (lane == 0) ? lds[0][0][0] : 0.f;
        a1 = (lane == 0 && Sl > 0) ? lds[0][0][1] : 0.f;
        {   // chunk 0: t=1 single, then pairs t=2..15
            float gs_ = fmaxf(a0, a1);
            single_step(&lds[0][1][0], lane, skf, a0, a1, aX);
            pair_step(&lds[0][2][0], &lds[0][3][0], lane, skf, skUf, skk, a0, a1, aX);
            pair_step(&lds[0][4][0], &lds[0][5][0], lane, skf, skUf, skk, a0, a1, aX);
            pair_step(&lds[0][6][0], &lds[0][7][0], lane, skf, skUf, skk, a0, a1, aX);
            renorm_apply(wave_max_bcast(gs_), a0, a1, aX, SH, 90);
            WIN4(0, 8);
        }
        __builtin_amdgcn_sched_barrier(0);
        ISSUE(2);
        for (int c = 1; c < NC; ++c) {
            if (c < NC - 1) asm volatile("s_waitcnt vmcnt(16)" ::: "memory");
            else            asm volatile("s_waitcnt vmcnt(0)"  ::: "memory");
            __builtin_amdgcn_sched_barrier(0);
            int buf = c & 1;
            WIN4(buf, 0);
            WIN4(buf, 8);
            if (c + 2 < NC) {
                __builtin_amdgcn_sched_barrier(0);
                ISSUE(c + 2);
            }
        }
    } else {
        // ---------------- generic fallback (R7 path, per-step) ----------------
#define GSTEP(cc, dd) do {                                                    \
    float cb_ = lds[(cc) & 1][dd][0];                                         \
    float cl_ = lds[(cc) & 1][dd][1 + lane];                                  \
    float p1_ = dpp_shr1_zero(a1);                                            \
    float na0_ = (a0 + p1_) * cb_;                                            \
    float na1_ = fmaf(skf, p1_, a0 + a1) * cl_;                               \
    float naX_ = (aX + a1) * cb_;                                             \
    int t_ = (cc) * CT + (dd);                                                \
    bool act_ = (unsigned)(t_ - 1) < (unsigned)(Tin - 1);                     \
    a0 = act_ ? na0_ : a0;                                                    \
    a1 = act_ ? na1_ : a1;                                                    \
    aX = act_ ? naX_ : aX;                                                    \
    if (((dd) & 3) == 3) {                                                    \
        float g_ = wave_max_bcast(fmaxf(a0, fmaxf(a1, aX)));                  \
        renorm_apply(g_, a0, a1, aX, SH, 100);                                \
    }                                                                         \
} while (0)
        asm volatile("s_waitcnt vmcnt(16)" ::: "memory");
        __builtin_amdgcn_sched_barrier(0);
        a0 = (lane == 0) ? lds[0][0][0] : 0.f;
        a1 = (lane == 0 && Sl > 0) ? lds[0][0][1] : 0.f;
        #pragma unroll
        for (int d = 1; d < CT; ++d) GSTEP(0, d);
        __builtin_amdgcn_sched_barrier(0);
        ISSUE(2);
        for (int c = 1; c < NC; ++c) {
            if (c < NC - 1) asm volatile("s_waitcnt vmcnt(16)" ::: "memory");
            else            asm volatile("s_waitcnt vmcnt(0)"  ::: "memory");
            __builtin_amdgcn_sched_barrier(0);
            #pragma unroll
            for (int d = 0; d < CT; ++d) GSTEP(c, d);
            if (c + 2 < NC) {
                __builtin_amdgcn_sched_barrier(0);
                ISSUE(c + 2);
            }
        }
#undef GSTEP
    }
#undef ISSUE
#undef WIN4

    // loss_n = -log(alpha[2*Sl] + alpha[2*Sl-1]) with accumulated 2^SH scale
    float a_last = (Sl >= S) ? __shfl(aX, 63) : __shfl(a0, Sl);
    float a_prev_raw = __shfl(a1, (Sl > 0) ? (Sl - 1) : 0);
    float a_prev = (Sl > 0) ? a_prev_raw : 0.f;
    if (lane == 0) {
        float sum  = a_last + a_prev;
        float ll2  = log2f(sum) - (float)SH;           // log2 P
        float loss = -ll2 * LN2;
        if (!(loss < 5e29f)) loss = 0.f;               // zero_infinity (+NaN)
        loss_out[n] = loss;
    }
}

// ---------------- Kernel 3: final sum ---------------------------------------
__global__ __launch_bounds__(64) void k_reduce(
    const float* __restrict__ loss, float* __restrict__ out)
{
    int lane = threadIdx.x;
    float v = (lane < N) ? loss[lane] : 0.f;
    for (int off = 32; off; off >>= 1) v += __shfl_xor(v, off);
    if (lane == 0) out[0] = v;
}

extern "C" void kernel_launch(void* const* d_in, const int* in_sizes, int n_in,
                              void* d_out, int out_size, void* d_ws, size_t ws_size,
                              hipStream_t stream) {
    const float* x       = (const float*)d_in[0];
    const int*   labels  = (const int*)d_in[1];
    const int*   in_len  = (const int*)d_in[2];
    const int*   lab_len = (const int*)d_in[3];
    float* out  = (float*)d_out;
    float* pp   = (float*)d_ws;                          // TN*ROWF floats
    float* loss = pp + (size_t)TN * ROWF + 256;          // +1KB pad (DMA over-read)

    k_softmax_probs<<<TN / 4, 256, 0, stream>>>(x, labels, pp);
    k_ctc_alpha<<<N, 64, 0, stream>>>(pp, labels, in_len, lab_len, loss);
    k_reduce<<<1, 64, 0, stream>>>(loss, out);
}